// Round 8
// baseline (381.703 us; speedup 1.0000x reference)
//
#include <hip/hip_runtime.h>

#define N_NODES 50000
#define FEAT    128
#define NEDGE   600000
#define BLK_PER_HALF 782   // ceil(50000/64)

#define NBUK    196        // buckets per rel (256 dsts each); 588 total
#define NBUKT   588
#define BUKCAP  4096       // bucket total: mean 3061, sigma 55 -> 19 sigma
#define KPART   256        // partition blocks (private regions); == block size
#define SEGCAP  56         // per (block,bucket): mean 12, Chernoff P(>=56)~5e-19
#define EPB     2344       // ceil(600000/256) edges per partition block
#define NB_CVT  6250       // 2 x 3125
#define NB_W    5

typedef __attribute__((ext_vector_type(8))) short short8;
typedef __attribute__((ext_vector_type(4))) float f32x4;

// ---------- bf16 helpers ----------
__device__ __forceinline__ unsigned short f2bf(float f) {
  unsigned u = __float_as_uint(f);
  return (unsigned short)((u + 0x7fffu + ((u >> 16) & 1u)) >> 16);
}
__device__ __forceinline__ float bflo(unsigned u) { return __uint_as_float(u << 16); }
__device__ __forceinline__ float bfhi(unsigned u) { return __uint_as_float(u & 0xffff0000u); }

// ---------- edge dtype handling ----------
__global__ void detect_i64(const unsigned int* __restrict__ e, int* __restrict__ flag) {
  unsigned int hi = e[2 * threadIdx.x + 1];
  unsigned long long any = __ballot(hi != 0u);
  if (threadIdx.x == 0) flag[0] = (any == 0ull) ? 1 : 0;
}
__device__ __forceinline__ int edge_at(const void* __restrict__ edges, long i, int is64) {
  return is64 ? (int)((const long long*)edges)[i] : ((const int*)edges)[i];
}

// ---------- fused: private-region partition + x->bf16 conversion + W pack ----------
__global__ __launch_bounds__(256) void part_cvt(
    const void* __restrict__ e0, const void* __restrict__ e1, const void* __restrict__ e2,
    unsigned* __restrict__ part, int* __restrict__ counts,
    const float* __restrict__ xu, const float* __restrict__ xi,
    const float* __restrict__ W_fol, const float* __restrict__ W_bb,
    const float* __restrict__ W_lu, const float* __restrict__ W_buy,
    const float* __restrict__ W_li,
    unsigned short* __restrict__ xu_b, unsigned short* __restrict__ xi_b,
    unsigned short* __restrict__ wfrag, const int* __restrict__ flag) {
  __shared__ int scnt[NBUKT];
  int b = blockIdx.x;
  int t = threadIdx.x;
  if (b < KPART) {
    for (int i = t; i < NBUKT; i += 256) scnt[i] = 0;
    __syncthreads();
    int is64 = *flag;
    const void* es[3] = {e0, e1, e2};
    int ebase = b * EPB;
    for (int i = t; i < EPB; i += 256) {
      int ei = ebase + i;
      if (ei >= NEDGE) break;
#pragma unroll
      for (int rel = 0; rel < 3; ++rel) {
        int src = edge_at(es[rel], ei, is64);
        int dst = edge_at(es[rel], NEDGE + ei, is64);
        int bk = rel * NBUK + (dst >> 8);
        int pos = atomicAdd(&scnt[bk], 1);
        if (pos < SEGCAP)
          part[(size_t)(b * NBUKT + bk) * SEGCAP + pos] =
              (unsigned)src | ((unsigned)(dst & 255) << 16);
      }
    }
    __syncthreads();
    for (int i = t; i < NBUKT; i += 256) counts[b * NBUKT + i] = min(scnt[i], SEGCAP);
  } else if (b < KPART + NB_CVT) {
    int cb = b - KPART;
    const float* src = (cb < 3125) ? xu : xi;
    unsigned short* dst = (cb < 3125) ? xu_b : xi_b;
    int lb = (cb < 3125) ? cb : cb - 3125;
    size_t base = ((size_t)lb * 256 + t) * 8;
    float4 v0 = *reinterpret_cast<const float4*>(src + base);
    float4 v1 = *reinterpret_cast<const float4*>(src + base + 4);
    uint4 o;
    o.x = f2bf(v0.x) | ((unsigned)f2bf(v0.y) << 16);
    o.y = f2bf(v0.z) | ((unsigned)f2bf(v0.w) << 16);
    o.z = f2bf(v1.x) | ((unsigned)f2bf(v1.y) << 16);
    o.w = f2bf(v1.z) | ((unsigned)f2bf(v1.w) << 16);
    *reinterpret_cast<uint4*>(dst + base) = o;
  } else {
    int s = b - (KPART + NB_CVT);
    const float* W = (s == 0) ? W_fol : (s == 1) ? W_bb : (s == 2) ? W_lu
                    : (s == 3) ? W_buy : W_li;
    for (int idx = t; idx < 16384; idx += 256) {
      int k = idx >> 7, n = idx & 127;
      int kc = k >> 5, q = (k >> 3) & 3, j = k & 7;
      int nt = n >> 4, nl = n & 15;
      wfrag[((((size_t)s * 4 + kc) * 8 + nt) * 64 + (q * 16 + nl)) * 8 + j] = f2bf(W[idx]);
    }
  }
}

// ---------- block scan helper ----------
__device__ __forceinline__ int block_scan_incl(int v, int* wsum) {
  int lane = threadIdx.x & 63, wid = threadIdx.x >> 6;
#pragma unroll
  for (int d = 1; d < 64; d <<= 1) {
    int n = __shfl_up(v, d, 64);
    if (lane >= d) v += n;
  }
  if (lane == 63) wsum[wid] = v;
  __syncthreads();
  if (threadIdx.x < 4) {
    int s = wsum[threadIdx.x];
#pragma unroll
    for (int d = 1; d < 4; d <<= 1) {
      int n = __shfl_up(s, d, 64);
      if ((int)threadIdx.x >= d) s += n;
    }
    wsum[threadIdx.x] = s;
  }
  __syncthreads();
  return v + (wid ? wsum[wid - 1] : 0);
}

// ---------- bucket totals + per-rel exclusive scan (3 blocks, one per rel) ----------
__global__ __launch_bounds__(256) void bucket_scan(
    const int* __restrict__ counts, int* __restrict__ bbase,
    int* __restrict__ rp0, int* __restrict__ rp1, int* __restrict__ rp2) {
  __shared__ int wsum[4];
  int rel = blockIdx.x;
  int t = threadIdx.x;
  int acc = 0;
  // coalesced: at fixed k, threads read 196 consecutive counts
  for (int k = 0; k < KPART; ++k)
    if (t < NBUK) acc += counts[k * NBUKT + rel * NBUK + t];
  int c = (t < NBUK) ? min(acc, BUKCAP) : 0;
  int incl = block_scan_incl(c, wsum);
  if (t < NBUK) bbase[rel * NBUK + t] = incl - c;
  if (t == 0) {
    int* rp = (rel == 0) ? rp0 : (rel == 1) ? rp1 : rp2;
    rp[N_NODES] = NEDGE;
  }
}

// ---------- per-bucket CSR build: 256 segments staged to LDS, full-width phases ----------
__global__ __launch_bounds__(256) void csr_build(
    const unsigned* __restrict__ part, const int* __restrict__ counts,
    const int* __restrict__ bbase,
    int* __restrict__ csr0, int* __restrict__ csr1, int* __restrict__ csr2,
    int* __restrict__ rp0, int* __restrict__ rp1, int* __restrict__ rp2) {
  __shared__ int segcnt[KPART];
  __shared__ int segoff[KPART];
  __shared__ int wsum[4];
  __shared__ int nTot;
  __shared__ unsigned stage[BUKCAP];     // 16 KB
  __shared__ int cnt[256];
  __shared__ int curs[256];
  __shared__ unsigned short img[BUKCAP]; // 8 KB
  int blk = blockIdx.x;
  int rel = blk / NBUK, lb = blk - rel * NBUK;
  int* __restrict__ csr = (rel == 0) ? csr0 : (rel == 1) ? csr1 : csr2;
  int* __restrict__ rp  = (rel == 0) ? rp0  : (rel == 1) ? rp1  : rp2;
  int t = threadIdx.x;

  // per-segment counts -> offsets (thread t owns segment k=t)
  int c = counts[t * NBUKT + blk];
  int incl = block_scan_incl(c, wsum);
  segcnt[t] = c;
  segoff[t] = incl - c;
  if (t == 255) nTot = incl;
  __syncthreads();
  int n = min(nTot, BUKCAP);

  // Phase A: waves copy the 256 segments into packed LDS stage
  int w = t >> 6, lane = t & 63;
  for (int k = w; k < KPART; k += 4) {
    int ck = segcnt[k], off = segoff[k];
    const unsigned* __restrict__ ent = part + (size_t)(k * NBUKT + blk) * SEGCAP;
    for (int i = lane; i < ck; i += 64)
      if (off + i < BUKCAP) stage[off + i] = ent[i];
  }
  cnt[t] = 0;
  __syncthreads();

  // Phase B: per-dst counts over stage (full 256-thread width)
  for (int i = t; i < n; i += 256)
    atomicAdd(&cnt[(stage[i] >> 16) & 255], 1);
  __syncthreads();
  int c2 = cnt[t];
  int incl2 = block_scan_incl(c2, wsum);
  int excl2 = incl2 - c2;
  curs[t] = excl2;
  int base = bbase[blk];
  int d = lb * 256 + t;
  if (d < N_NODES) rp[d] = base + excl2;
  __syncthreads();

  // Phase C: place into img, dump coalesced
  for (int i = t; i < n; i += 256) {
    unsigned en = stage[i];
    int pos = atomicAdd(&curs[(en >> 16) & 255], 1);
    img[pos] = (unsigned short)(en & 0xffffu);
  }
  __syncthreads();
  for (int i = t; i < n; i += 256)
    csr[base + i] = (int)img[i];
}

// ---------- gather-mean aggregation (bf16 in, fp32 accum, bf16 out) ----------
__global__ __launch_bounds__(256) void agg_all(
    const unsigned short* __restrict__ xu_b, const unsigned short* __restrict__ xi_b,
    const int* __restrict__ rp0, const int* __restrict__ rp1, const int* __restrict__ rp2,
    const int* __restrict__ csr0, const int* __restrict__ csr1, const int* __restrict__ csr2,
    unsigned short* __restrict__ aggF, unsigned short* __restrict__ aggBB,
    unsigned short* __restrict__ aggB) {
  int rel = blockIdx.x / 12500;
  int blk = blockIdx.x - rel * 12500;
  const unsigned short* x = (rel == 1) ? xi_b : xu_b;
  const int* rp  = (rel == 0) ? rp0  : (rel == 1) ? rp1  : rp2;
  const int* csr = (rel == 0) ? csr0 : (rel == 1) ? csr1 : csr2;
  unsigned short* agg = (rel == 0) ? aggF : (rel == 1) ? aggBB : aggB;

  int w = (blk * 256 + (int)threadIdx.x) >> 6;
  int lane = threadIdx.x & 63;
  const unsigned* __restrict__ xv = (const unsigned*)x;
  int beg = rp[w], end = rp[w + 1];
  float ax = 0.f, ay = 0.f;
  int e = beg;
  for (; e + 3 < end; e += 4) {
    int s0 = csr[e], s1 = csr[e + 1], s2 = csr[e + 2], s3 = csr[e + 3];
    unsigned u0 = xv[(size_t)s0 * 64 + lane];
    unsigned u1 = xv[(size_t)s1 * 64 + lane];
    unsigned u2 = xv[(size_t)s2 * 64 + lane];
    unsigned u3 = xv[(size_t)s3 * 64 + lane];
    ax += bflo(u0) + bflo(u1) + bflo(u2) + bflo(u3);
    ay += bfhi(u0) + bfhi(u1) + bfhi(u2) + bfhi(u3);
  }
  for (; e < end; ++e) {
    unsigned u = xv[(size_t)csr[e] * 64 + lane];
    ax += bflo(u); ay += bfhi(u);
  }
  float rd = 1.0f / fmaxf((float)(end - beg), 1.0f);
  ((unsigned*)agg)[(size_t)w * 64 + lane] =
      (unsigned)f2bf(ax * rd) | ((unsigned)f2bf(ay * rd) << 16);
}

// ---------- MFMA GEMM: out = relu(sum_s A_s @ W_s + bias), both halves ----------
__global__ __launch_bounds__(256) void mfma_gemm(
    const unsigned short* __restrict__ aggF, const unsigned short* __restrict__ aggBB,
    const unsigned short* __restrict__ aggB,
    const unsigned short* __restrict__ xu, const unsigned short* __restrict__ xi,
    const unsigned short* __restrict__ wfrag,
    const float* __restrict__ b_lu, const float* __restrict__ b_li,
    float* __restrict__ out) {
  __shared__ unsigned short As[8192];   // [rt(4)][kc(4)][lane(64)][8]
  const int t = threadIdx.x;
  const int b = blockIdx.x;
  const int half = (b >= BLK_PER_HALF) ? 1 : 0;
  const int g0 = (half ? b - BLK_PER_HALF : b) * 64;
  const int lane = t & 63;
  const int w = t >> 6;
  const int nsrc = half ? 2 : 3;
  const int widx0 = half ? 3 : 0;

  const unsigned short* A0 = half ? aggB : aggF;
  const unsigned short* A1 = half ? xi   : aggBB;
  const unsigned short* A2 = xu;

  f32x4 acc[4][2] = {};

  for (int s = 0; s < nsrc; ++s) {
    const unsigned short* A = (s == 0) ? A0 : (s == 1) ? A1 : A2;
#pragma unroll
    for (int i = 0; i < 4; ++i) {
      int idx = t + i * 256;
      int row = idx >> 4;
      int c8 = (idx & 15) << 3;
      int gr = g0 + row;
      float4 v = make_float4(0.f, 0.f, 0.f, 0.f);
      if (gr < N_NODES)
        v = *reinterpret_cast<const float4*>(A + (size_t)gr * FEAT + c8);
      int rt = row >> 4, m = row & 15;
      int kc = c8 >> 5, q = (c8 >> 3) & 3;
      *reinterpret_cast<float4*>(&As[((rt * 4 + kc) * 64 + (q * 16 + m)) * 8]) = v;
    }
    __syncthreads();
    const unsigned short* wf = wfrag + (size_t)(widx0 + s) * (4 * 8 * 64 * 8);
#pragma unroll
    for (int kc = 0; kc < 4; ++kc) {
      short8 bfr[2];
#pragma unroll
      for (int ct = 0; ct < 2; ++ct) {
        int nt = 2 * w + ct;
        bfr[ct] = *reinterpret_cast<const short8*>(wf + ((kc * 8 + nt) * 64 + lane) * 8);
      }
#pragma unroll
      for (int rt = 0; rt < 4; ++rt) {
        short8 afr = *reinterpret_cast<const short8*>(&As[((rt * 4 + kc) * 64 + lane) * 8]);
#pragma unroll
        for (int ct = 0; ct < 2; ++ct)
          acc[rt][ct] = __builtin_amdgcn_mfma_f32_16x16x32_bf16(afr, bfr[ct],
                                                                acc[rt][ct], 0, 0, 0);
      }
    }
    __syncthreads();
  }

  const float* bias = half ? b_li : b_lu;
  int q = lane >> 4, nl = lane & 15;
  float bv[2] = { bias[w * 32 + nl], bias[w * 32 + 16 + nl] };
#pragma unroll
  for (int rt = 0; rt < 4; ++rt)
#pragma unroll
    for (int r = 0; r < 4; ++r) {
      int gr = g0 + rt * 16 + q * 4 + r;
      if (gr < N_NODES) {
        size_t orow = (size_t)(half ? N_NODES : 0) + gr;
#pragma unroll
        for (int ct = 0; ct < 2; ++ct) {
          float v = acc[rt][ct][r] + bv[ct];
          out[orow * FEAT + w * 32 + ct * 16 + nl] = fmaxf(v, 0.f);
        }
      }
    }
}

extern "C" void kernel_launch(void* const* d_in, const int* in_sizes, int n_in,
                              void* d_out, int out_size, void* d_ws, size_t ws_size,
                              hipStream_t stream) {
  const float* x_user = (const float*)d_in[0];
  const float* x_item = (const float*)d_in[1];
  const void* e_fol = d_in[2];
  const void* e_buy = d_in[3];
  const void* e_bb  = d_in[4];
  const float* W_fol = (const float*)d_in[5];
  const float* W_buy = (const float*)d_in[6];
  const float* W_bb  = (const float*)d_in[7];
  const float* W_lu  = (const float*)d_in[8];
  const float* b_lu  = (const float*)d_in[9];
  const float* W_li  = (const float*)d_in[10];
  const float* b_li  = (const float*)d_in[11];
  float* out = (float*)d_out;

  // ws: bf16 arrays (64.16 MB) then ints (~8.4 MB). part (33.7 MB) ALIASES
  // aggF/aggBB/aggB -- part is dead before agg_all writes them (stream order).
  unsigned short* wsu = (unsigned short*)d_ws;
  unsigned short* aggF  = wsu;
  unsigned short* aggBB = wsu + 6400000;
  unsigned short* aggB  = wsu + 12800000;
  unsigned short* xu_b  = wsu + 19200000;
  unsigned short* xi_b  = wsu + 25600000;
  unsigned short* wfrag = wsu + 32000000;      // 81920 ushorts
  unsigned* part = (unsigned*)d_ws;            // KPART*NBUKT*SEGCAP = 8,429,568 uints
  int* ip = (int*)d_ws + 16040960;
  int* csr0 = ip;
  int* csr1 = ip + 600000;
  int* csr2 = ip + 1200000;
  int* rp0  = ip + 1800000;     // 50016 each
  int* rp1  = rp0 + 50016;
  int* rp2  = rp1 + 50016;
  int* counts = ip + 1950048;   // KPART*NBUKT = 150528
  int* bbase  = ip + 2100576;   // 588
  int* flag   = ip + 2101164;

  detect_i64<<<1, 64, 0, stream>>>((const unsigned int*)e_fol, flag);

  part_cvt<<<KPART + NB_CVT + NB_W, 256, 0, stream>>>(
      e_fol, e_bb, e_buy, part, counts, x_user, x_item,
      W_fol, W_bb, W_lu, W_buy, W_li, xu_b, xi_b, wfrag, flag);

  bucket_scan<<<3, 256, 0, stream>>>(counts, bbase, rp0, rp1, rp2);

  csr_build<<<3 * NBUK, 256, 0, stream>>>(part, counts, bbase,
                                          csr0, csr1, csr2, rp0, rp1, rp2);

  agg_all<<<3 * 12500, 256, 0, stream>>>(xu_b, xi_b, rp0, rp1, rp2,
                                         csr0, csr1, csr2, aggF, aggBB, aggB);

  mfma_gemm<<<2 * BLK_PER_HALF, 256, 0, stream>>>(
      aggF, aggBB, aggB, xu_b, xi_b, wfrag, b_lu, b_li, out);
}

// Round 9
// 306.692 us; speedup vs baseline: 1.2446x; 1.2446x over previous
//
#include <hip/hip_runtime.h>

#define N_NODES 50000
#define FEAT    128
#define NEDGE   600000
#define BLK_PER_HALF 782   // ceil(50000/64)

#define NBUK    196        // buckets per rel (256 dsts each); 588 total
#define NBUKT   588
#define BUKCAP  4096       // bucket total: mean 3061, sigma 55 -> 19 sigma
#define KPART   224        // partition blocks
#define SEGCAP  64         // 256 B: line-aligned, XCD-private; mean 13.7 -> ~12 sigma
#define EPB     2679       // ceil(600000/224)
#define NB_CVT  6250       // 2 x 3125
#define NB_W    5

typedef __attribute__((ext_vector_type(8))) short short8;
typedef __attribute__((ext_vector_type(4))) float f32x4;

// ---------- bf16 helpers ----------
__device__ __forceinline__ unsigned short f2bf(float f) {
  unsigned u = __float_as_uint(f);
  return (unsigned short)((u + 0x7fffu + ((u >> 16) & 1u)) >> 16);
}
__device__ __forceinline__ float bflo(unsigned u) { return __uint_as_float(u << 16); }
__device__ __forceinline__ float bfhi(unsigned u) { return __uint_as_float(u & 0xffff0000u); }

// ---------- edge dtype handling ----------
__global__ void detect_i64(const unsigned int* __restrict__ e, int* __restrict__ flag) {
  unsigned int hi = e[2 * threadIdx.x + 1];
  unsigned long long any = __ballot(hi != 0u);
  if (threadIdx.x == 0) flag[0] = (any == 0ull) ? 1 : 0;
}
__device__ __forceinline__ int edge_at(const void* __restrict__ edges, long i, int is64) {
  return is64 ? (int)((const long long*)edges)[i] : ((const int*)edges)[i];
}

// ---------- fused: private-region partition + x->bf16 conversion + W pack ----------
// part layout TRANSPOSED: part[(bucket*KPART + block)*SEGCAP + pos]
// -> a bucket's 224 segments are one contiguous 56 KB region for csr_build.
__global__ __launch_bounds__(256) void part_cvt(
    const void* __restrict__ e0, const void* __restrict__ e1, const void* __restrict__ e2,
    unsigned* __restrict__ part, int* __restrict__ countsT,
    const float* __restrict__ xu, const float* __restrict__ xi,
    const float* __restrict__ W_fol, const float* __restrict__ W_bb,
    const float* __restrict__ W_lu, const float* __restrict__ W_buy,
    const float* __restrict__ W_li,
    unsigned short* __restrict__ xu_b, unsigned short* __restrict__ xi_b,
    unsigned short* __restrict__ wfrag, const int* __restrict__ flag) {
  __shared__ int scnt[NBUKT];
  int b = blockIdx.x;
  int t = threadIdx.x;
  if (b < KPART) {
    for (int i = t; i < NBUKT; i += 256) scnt[i] = 0;
    __syncthreads();
    int is64 = *flag;
    const void* es[3] = {e0, e1, e2};
    int ebase = b * EPB;
    for (int i = t; i < EPB; i += 256) {
      int ei = ebase + i;
      if (ei >= NEDGE) break;
#pragma unroll
      for (int rel = 0; rel < 3; ++rel) {
        int src = edge_at(es[rel], ei, is64);
        int dst = edge_at(es[rel], NEDGE + ei, is64);
        int bk = rel * NBUK + (dst >> 8);
        int pos = atomicAdd(&scnt[bk], 1);
        if (pos < SEGCAP)
          part[((size_t)bk * KPART + b) * SEGCAP + pos] =
              (unsigned)src | ((unsigned)(dst & 255) << 16);
      }
    }
    __syncthreads();
    for (int i = t; i < NBUKT; i += 256)
      countsT[i * KPART + b] = min(scnt[i], SEGCAP);
  } else if (b < KPART + NB_CVT) {
    int cb = b - KPART;
    const float* src = (cb < 3125) ? xu : xi;
    unsigned short* dst = (cb < 3125) ? xu_b : xi_b;
    int lb = (cb < 3125) ? cb : cb - 3125;
    size_t base = ((size_t)lb * 256 + t) * 8;
    float4 v0 = *reinterpret_cast<const float4*>(src + base);
    float4 v1 = *reinterpret_cast<const float4*>(src + base + 4);
    uint4 o;
    o.x = f2bf(v0.x) | ((unsigned)f2bf(v0.y) << 16);
    o.y = f2bf(v0.z) | ((unsigned)f2bf(v0.w) << 16);
    o.z = f2bf(v1.x) | ((unsigned)f2bf(v1.y) << 16);
    o.w = f2bf(v1.z) | ((unsigned)f2bf(v1.w) << 16);
    *reinterpret_cast<uint4*>(dst + base) = o;
  } else {
    int s = b - (KPART + NB_CVT);
    const float* W = (s == 0) ? W_fol : (s == 1) ? W_bb : (s == 2) ? W_lu
                    : (s == 3) ? W_buy : W_li;
    for (int idx = t; idx < 16384; idx += 256) {
      int k = idx >> 7, n = idx & 127;
      int kc = k >> 5, q = (k >> 3) & 3, j = k & 7;
      int nt = n >> 4, nl = n & 15;
      wfrag[((((size_t)s * 4 + kc) * 8 + nt) * 64 + (q * 16 + nl)) * 8 + j] = f2bf(W[idx]);
    }
  }
}

// ---------- block scan helper ----------
__device__ __forceinline__ int block_scan_incl(int v, int* wsum) {
  int lane = threadIdx.x & 63, wid = threadIdx.x >> 6;
#pragma unroll
  for (int d = 1; d < 64; d <<= 1) {
    int n = __shfl_up(v, d, 64);
    if (lane >= d) v += n;
  }
  if (lane == 63) wsum[wid] = v;
  __syncthreads();
  if (threadIdx.x < 4) {
    int s = wsum[threadIdx.x];
#pragma unroll
    for (int d = 1; d < 4; d <<= 1) {
      int n = __shfl_up(s, d, 64);
      if ((int)threadIdx.x >= d) s += n;
    }
    wsum[threadIdx.x] = s;
  }
  __syncthreads();
  return v + (wid ? wsum[wid - 1] : 0);
}

// ---------- bucket totals + per-rel exclusive scan (3 blocks, one per rel) ----------
__global__ __launch_bounds__(256) void bucket_scan(
    const int* __restrict__ countsT, int* __restrict__ bbase,
    int* __restrict__ rp0, int* __restrict__ rp1, int* __restrict__ rp2) {
  __shared__ int wsum[4];
  int rel = blockIdx.x;
  int t = threadIdx.x;
  int acc = 0;
  if (t < NBUK) {
    const int* c = countsT + (size_t)(rel * NBUK + t) * KPART;
    for (int k = 0; k < KPART; ++k) acc += c[k];
  }
  int c = (t < NBUK) ? min(acc, BUKCAP) : 0;
  int incl = block_scan_incl(c, wsum);
  if (t < NBUK) bbase[rel * NBUK + t] = incl - c;
  if (t == 0) {
    int* rp = (rel == 0) ? rp0 : (rel == 1) ? rp1 : rp2;
    rp[N_NODES] = NEDGE;
  }
}

// ---------- per-bucket CSR build: contiguous 56 KB stage read, full-width phases ----------
__global__ __launch_bounds__(256) void csr_build(
    const unsigned* __restrict__ part, const int* __restrict__ countsT,
    const int* __restrict__ bbase,
    int* __restrict__ csr0, int* __restrict__ csr1, int* __restrict__ csr2,
    int* __restrict__ rp0, int* __restrict__ rp1, int* __restrict__ rp2) {
  __shared__ int segcnt[256];
  __shared__ int segoff[256];
  __shared__ int wsum[4];
  __shared__ int nTot;
  __shared__ unsigned stage[BUKCAP];     // 16 KB
  __shared__ int cnt[256];
  __shared__ int curs[256];
  __shared__ unsigned short img[BUKCAP]; // 8 KB
  int blk = blockIdx.x;
  int rel = blk / NBUK, lb = blk - rel * NBUK;
  int* __restrict__ csr = (rel == 0) ? csr0 : (rel == 1) ? csr1 : csr2;
  int* __restrict__ rp  = (rel == 0) ? rp0  : (rel == 1) ? rp1  : rp2;
  int t = threadIdx.x;

  // per-segment counts -> packed offsets
  int c = (t < KPART) ? countsT[(size_t)blk * KPART + t] : 0;
  int incl = block_scan_incl(c, wsum);
  segcnt[t] = c;
  segoff[t] = incl - c;
  if (t == 255) nTot = incl;
  __syncthreads();
  int n = min(nTot, BUKCAP);

  // Phase A: coalesced read of the bucket's contiguous region, compact into stage
  const unsigned* __restrict__ reg = part + (size_t)blk * KPART * SEGCAP;
  for (int i = t; i < KPART * SEGCAP; i += 256) {
    int k = i >> 6, j = i & (SEGCAP - 1);
    if (j < segcnt[k]) stage[segoff[k] + j] = reg[i];
  }
  cnt[t] = 0;
  __syncthreads();

  // Phase B: per-dst counts over stage
  for (int i = t; i < n; i += 256)
    atomicAdd(&cnt[(stage[i] >> 16) & 255], 1);
  __syncthreads();
  int c2 = cnt[t];
  int incl2 = block_scan_incl(c2, wsum);
  int excl2 = incl2 - c2;
  curs[t] = excl2;
  int base = bbase[blk];
  int d = lb * 256 + t;
  if (d < N_NODES) rp[d] = base + excl2;
  __syncthreads();

  // Phase C: place into img, dump coalesced
  for (int i = t; i < n; i += 256) {
    unsigned en = stage[i];
    int pos = atomicAdd(&curs[(en >> 16) & 255], 1);
    img[pos] = (unsigned short)(en & 0xffffu);
  }
  __syncthreads();
  for (int i = t; i < n; i += 256)
    csr[base + i] = (int)img[i];
}

// ---------- gather-mean aggregation: uint4 gathers, 4 edges per load instr ----------
__global__ __launch_bounds__(256) void agg_all(
    const unsigned short* __restrict__ xu_b, const unsigned short* __restrict__ xi_b,
    const int* __restrict__ rp0, const int* __restrict__ rp1, const int* __restrict__ rp2,
    const int* __restrict__ csr0, const int* __restrict__ csr1, const int* __restrict__ csr2,
    unsigned short* __restrict__ aggF, unsigned short* __restrict__ aggBB,
    unsigned short* __restrict__ aggB) {
  int rel = blockIdx.x / 12500;
  int blk = blockIdx.x - rel * 12500;
  const unsigned short* x = (rel == 1) ? xi_b : xu_b;
  const int* rp  = (rel == 0) ? rp0  : (rel == 1) ? rp1  : rp2;
  const int* csr = (rel == 0) ? csr0 : (rel == 1) ? csr1 : csr2;
  unsigned short* agg = (rel == 0) ? aggF : (rel == 1) ? aggBB : aggB;

  int w = (blk * 256 + (int)threadIdx.x) >> 6;   // dst row, one wave per row
  int lane = threadIdx.x & 63;
  int sub = lane & 15, grp = lane >> 4;          // 16 lanes x 16 B = one 256 B row
  const uint4* __restrict__ xv = (const uint4*)x;
  int beg = rp[w], end = rp[w + 1];
  float a0 = 0, a1 = 0, a2 = 0, a3 = 0, a4 = 0, a5 = 0, a6 = 0, a7 = 0;
  for (int e = beg + grp; e < end; e += 4) {
    uint4 v = xv[(size_t)csr[e] * 16 + sub];
    a0 += bflo(v.x); a1 += bfhi(v.x);
    a2 += bflo(v.y); a3 += bfhi(v.y);
    a4 += bflo(v.z); a5 += bfhi(v.z);
    a6 += bflo(v.w); a7 += bfhi(v.w);
  }
#define RED16_32(a) { a += __shfl_xor(a, 16, 64); a += __shfl_xor(a, 32, 64); }
  RED16_32(a0) RED16_32(a1) RED16_32(a2) RED16_32(a3)
  RED16_32(a4) RED16_32(a5) RED16_32(a6) RED16_32(a7)
#undef RED16_32
  if (grp == 0) {
    float rd = 1.0f / fmaxf((float)(end - beg), 1.0f);
    uint4 o;
    o.x = (unsigned)f2bf(a0 * rd) | ((unsigned)f2bf(a1 * rd) << 16);
    o.y = (unsigned)f2bf(a2 * rd) | ((unsigned)f2bf(a3 * rd) << 16);
    o.z = (unsigned)f2bf(a4 * rd) | ((unsigned)f2bf(a5 * rd) << 16);
    o.w = (unsigned)f2bf(a6 * rd) | ((unsigned)f2bf(a7 * rd) << 16);
    ((uint4*)agg)[(size_t)w * 16 + sub] = o;
  }
}

// ---------- MFMA GEMM: out = relu(sum_s A_s @ W_s + bias), both halves ----------
__global__ __launch_bounds__(256) void mfma_gemm(
    const unsigned short* __restrict__ aggF, const unsigned short* __restrict__ aggBB,
    const unsigned short* __restrict__ aggB,
    const unsigned short* __restrict__ xu, const unsigned short* __restrict__ xi,
    const unsigned short* __restrict__ wfrag,
    const float* __restrict__ b_lu, const float* __restrict__ b_li,
    float* __restrict__ out) {
  __shared__ unsigned short As[8192];   // [rt(4)][kc(4)][lane(64)][8]
  const int t = threadIdx.x;
  const int b = blockIdx.x;
  const int half = (b >= BLK_PER_HALF) ? 1 : 0;
  const int g0 = (half ? b - BLK_PER_HALF : b) * 64;
  const int lane = t & 63;
  const int w = t >> 6;
  const int nsrc = half ? 2 : 3;
  const int widx0 = half ? 3 : 0;

  const unsigned short* A0 = half ? aggB : aggF;
  const unsigned short* A1 = half ? xi   : aggBB;
  const unsigned short* A2 = xu;

  f32x4 acc[4][2] = {};

  for (int s = 0; s < nsrc; ++s) {
    const unsigned short* A = (s == 0) ? A0 : (s == 1) ? A1 : A2;
#pragma unroll
    for (int i = 0; i < 4; ++i) {
      int idx = t + i * 256;
      int row = idx >> 4;
      int c8 = (idx & 15) << 3;
      int gr = g0 + row;
      float4 v = make_float4(0.f, 0.f, 0.f, 0.f);
      if (gr < N_NODES)
        v = *reinterpret_cast<const float4*>(A + (size_t)gr * FEAT + c8);
      int rt = row >> 4, m = row & 15;
      int kc = c8 >> 5, q = (c8 >> 3) & 3;
      *reinterpret_cast<float4*>(&As[((rt * 4 + kc) * 64 + (q * 16 + m)) * 8]) = v;
    }
    __syncthreads();
    const unsigned short* wf = wfrag + (size_t)(widx0 + s) * (4 * 8 * 64 * 8);
#pragma unroll
    for (int kc = 0; kc < 4; ++kc) {
      short8 bfr[2];
#pragma unroll
      for (int ct = 0; ct < 2; ++ct) {
        int nt = 2 * w + ct;
        bfr[ct] = *reinterpret_cast<const short8*>(wf + ((kc * 8 + nt) * 64 + lane) * 8);
      }
#pragma unroll
      for (int rt = 0; rt < 4; ++rt) {
        short8 afr = *reinterpret_cast<const short8*>(&As[((rt * 4 + kc) * 64 + lane) * 8]);
#pragma unroll
        for (int ct = 0; ct < 2; ++ct)
          acc[rt][ct] = __builtin_amdgcn_mfma_f32_16x16x32_bf16(afr, bfr[ct],
                                                                acc[rt][ct], 0, 0, 0);
      }
    }
    __syncthreads();
  }

  const float* bias = half ? b_li : b_lu;
  int q = lane >> 4, nl = lane & 15;
  float bv[2] = { bias[w * 32 + nl], bias[w * 32 + 16 + nl] };
#pragma unroll
  for (int rt = 0; rt < 4; ++rt)
#pragma unroll
    for (int r = 0; r < 4; ++r) {
      int gr = g0 + rt * 16 + q * 4 + r;
      if (gr < N_NODES) {
        size_t orow = (size_t)(half ? N_NODES : 0) + gr;
#pragma unroll
        for (int ct = 0; ct < 2; ++ct) {
          float v = acc[rt][ct][r] + bv[ct];
          out[orow * FEAT + w * 32 + ct * 16 + nl] = fmaxf(v, 0.f);
        }
      }
    }
}

extern "C" void kernel_launch(void* const* d_in, const int* in_sizes, int n_in,
                              void* d_out, int out_size, void* d_ws, size_t ws_size,
                              hipStream_t stream) {
  const float* x_user = (const float*)d_in[0];
  const float* x_item = (const float*)d_in[1];
  const void* e_fol = d_in[2];
  const void* e_buy = d_in[3];
  const void* e_bb  = d_in[4];
  const float* W_fol = (const float*)d_in[5];
  const float* W_buy = (const float*)d_in[6];
  const float* W_bb  = (const float*)d_in[7];
  const float* W_lu  = (const float*)d_in[8];
  const float* b_lu  = (const float*)d_in[9];
  const float* W_li  = (const float*)d_in[10];
  const float* b_li  = (const float*)d_in[11];
  float* out = (float*)d_out;

  // ws: bf16 arrays (64.16 MB) then ints (~8.4 MB). part (33.7 MB) ALIASES
  // aggF/aggBB/aggB (38.4 MB) -- part is dead before agg_all writes them.
  unsigned short* wsu = (unsigned short*)d_ws;
  unsigned short* aggF  = wsu;
  unsigned short* aggBB = wsu + 6400000;
  unsigned short* aggB  = wsu + 12800000;
  unsigned short* xu_b  = wsu + 19200000;
  unsigned short* xi_b  = wsu + 25600000;
  unsigned short* wfrag = wsu + 32000000;      // 81920 ushorts
  unsigned* part = (unsigned*)d_ws;            // NBUKT*KPART*SEGCAP = 8,429,568 uints
  int* ip = (int*)d_ws + 16040960;
  int* csr0 = ip;
  int* csr1 = ip + 600000;
  int* csr2 = ip + 1200000;
  int* rp0  = ip + 1800000;     // 50016 each
  int* rp1  = rp0 + 50016;
  int* rp2  = rp1 + 50016;
  int* countsT = ip + 1950048;  // NBUKT*KPART = 131712
  int* bbase   = ip + 2081760;  // 588
  int* flag    = ip + 2082348;

  detect_i64<<<1, 64, 0, stream>>>((const unsigned int*)e_fol, flag);

  part_cvt<<<KPART + NB_CVT + NB_W, 256, 0, stream>>>(
      e_fol, e_bb, e_buy, part, countsT, x_user, x_item,
      W_fol, W_bb, W_lu, W_buy, W_li, xu_b, xi_b, wfrag, flag);

  bucket_scan<<<3, 256, 0, stream>>>(countsT, bbase, rp0, rp1, rp2);

  csr_build<<<3 * NBUK, 256, 0, stream>>>(part, countsT, bbase,
                                          csr0, csr1, csr2, rp0, rp1, rp2);

  agg_all<<<3 * 12500, 256, 0, stream>>>(xu_b, xi_b, rp0, rp1, rp2,
                                         csr0, csr1, csr2, aggF, aggBB, aggB);

  mfma_gemm<<<2 * BLK_PER_HALF, 256, 0, stream>>>(
      aggF, aggBB, aggB, xu_b, xi_b, wfrag, b_lu, b_li, out);
}